// Round 4
// baseline (52.334 us; speedup 1.0000x reference)
//
#include <hip/hip_runtime.h>

namespace {

constexpr int IMGW  = 512;
constexpr int NIMG  = 16;
constexpr int C1N   = 16;
constexpr int C2N   = 32;
constexpr int PART  = C1N * 9;   // 144 partial scalars per patch-row
constexpr int NROWS = 1024;      // total patch-rows (16 img x 64)
constexpr int NBLK  = NROWS * 4; // 4 channel-quads per patch-row, 1 wave each

// Fast orthonormal 8-pt DCT-II (even/odd butterfly).
__device__ __forceinline__ void dct8(const float x[8], float o[8]) {
  const float c1 = 0.49039264020161522f;
  const float c2 = 0.46193976625564337f;
  const float c3 = 0.41573480615127262f;
  const float c4 = 0.35355339059327373f;
  const float c5 = 0.27778511650980111f;
  const float c6 = 0.19134171618254492f;
  const float c7 = 0.09754516100806413f;
  const float s0 = x[0] + x[7], s1 = x[1] + x[6], s2 = x[2] + x[5], s3 = x[3] + x[4];
  const float d0 = x[0] - x[7], d1 = x[1] - x[6], d2 = x[2] - x[5], d3 = x[3] - x[4];
  const float e0 = s0 + s3, e1 = s1 + s2, e2 = s0 - s3, e3 = s1 - s2;
  o[0] = c4 * (e0 + e1);
  o[4] = c4 * (e0 - e1);
  o[2] = fmaf(c2, e2,  c6 * e3);
  o[6] = fmaf(c6, e2, -(c2 * e3));
  o[1] = fmaf(c1, d0, fmaf( c3, d1, fmaf( c5, d2,  c7 * d3)));
  o[3] = fmaf(c3, d0, fmaf(-c7, d1, fmaf(-c1, d2, -(c5 * d3))));
  o[5] = fmaf(c5, d0, fmaf(-c1, d1, fmaf( c7, d2,  c3 * d3)));
  o[7] = fmaf(c7, d0, fmaf(-c5, d1, fmaf( c3, d2, -(c1 * d3))));
}

// One block = ONE wave = one patch-row (64 patches, lane = patch column)
// x 4 conv1 channels. 4096 single-wave blocks -> fine-grained scheduling.
// GROUPS=4: reduce only within 16-lane groups (DPP-only shuffles, no
// bpermute); finish kernel sums the 4 group-partials. GROUPS=1: full reduce.
template<int GROUPS>
__global__ __launch_bounds__(64, 4) void dct_conv_kernel(
    const float* __restrict__ x, const float* __restrict__ w1,
    const float* __restrict__ b1, float* __restrict__ partials)
{
  const int blk  = blockIdx.x;
  const int prow = blk >> 2;          // img*64 + row
  const int quad = blk & 3;
  const int img  = prow >> 6;
  const int row  = prow & 63;
  const int lane = threadIdx.x;       // 0..63 = patch column
  const int ch0  = quad * 4;

  float w[4][9], bb[4];
  #pragma unroll
  for (int cc = 0; cc < 4; ++cc) {
    #pragma unroll
    for (int q = 0; q < 9; ++q) w[cc][q] = w1[(ch0 + cc) * 9 + q];
    bb[cc] = b1[ch0 + cc];
  }

  const float* base = x + ((size_t)img * IMGW + (size_t)row * 8) * IMGW + (size_t)lane * 8;

  float p[8][8];
  #pragma unroll
  for (int r = 0; r < 8; ++r) {
    const float4 a = *reinterpret_cast<const float4*>(base + (size_t)r * IMGW);
    const float4 b = *reinterpret_cast<const float4*>(base + (size_t)r * IMGW + 4);
    p[r][0] = a.x; p[r][1] = a.y; p[r][2] = a.z; p[r][3] = a.w;
    p[r][4] = b.x; p[r][5] = b.y; p[r][6] = b.z; p[r][7] = b.w;
  }

  // 2D DCT: t = D*p (column-wise), cf = t*D^T (row-wise)
  float t[8][8];
  #pragma unroll
  for (int j = 0; j < 8; ++j) {
    float xin[8], xo[8];
    #pragma unroll
    for (int k = 0; k < 8; ++k) xin[k] = p[k][j];
    dct8(xin, xo);
    #pragma unroll
    for (int k = 0; k < 8; ++k) t[k][j] = xo[k];
  }
  float cf[8][8];
  #pragma unroll
  for (int i = 0; i < 8; ++i) {
    float xo[8];
    dct8(t[i], xo);
    #pragma unroll
    for (int k = 0; k < 8; ++k) cf[i][k] = xo[k];
  }

  // conv1 3x3 SAME + ReLU, row-structured; reduce+store per channel so the
  // shuffle latency overlaps the next channel's FMAs.
  #pragma unroll
  for (int cc = 0; cc < 4; ++cc) {
    const float bbc = bb[cc];
    float T = 0.f, C0 = 0.f, C7 = 0.f;
    float R0 = 0.f, R7 = 0.f, K00 = 0.f, K07 = 0.f, K70 = 0.f, K77 = 0.f;
    #pragma unroll
    for (int i = 0; i < 8; ++i) {
      float a[8];
      #pragma unroll
      for (int j = 0; j < 8; ++j) a[j] = bbc;
      #pragma unroll
      for (int di = 0; di < 3; ++di) {
        const int ii = i + di - 1;
        if (ii >= 0 && ii < 8) {
          const float w0 = w[cc][di * 3 + 0];
          const float w1_ = w[cc][di * 3 + 1];
          const float w2_ = w[cc][di * 3 + 2];
          a[0] = fmaf(w1_, cf[ii][0], fmaf(w2_, cf[ii][1], a[0]));
          #pragma unroll
          for (int j = 1; j < 7; ++j)
            a[j] = fmaf(w0, cf[ii][j - 1], fmaf(w1_, cf[ii][j], fmaf(w2_, cf[ii][j + 1], a[j])));
          a[7] = fmaf(w0, cf[ii][6], fmaf(w1_, cf[ii][7], a[7]));
        }
      }
      #pragma unroll
      for (int j = 0; j < 8; ++j) a[j] = fmaxf(a[j], 0.f);
      const float rs = ((a[0] + a[1]) + (a[2] + a[3])) + ((a[4] + a[5]) + (a[6] + a[7]));
      T += rs;
      C0 += a[0]; C7 += a[7];
      if (i == 0) { R0 = rs; K00 = a[0]; K07 = a[7]; }
      if (i == 7) { R7 = rs; K70 = a[0]; K77 = a[7]; }
    }

    float v[9] = {T, R0, R7, C0, C7, K00, K07, K70, K77};
    if (GROUPS == 4) {
      #pragma unroll
      for (int q = 0; q < 9; ++q) {
        float s = v[q];
        s += __shfl_xor(s, 1); s += __shfl_xor(s, 2);
        s += __shfl_xor(s, 4); s += __shfl_xor(s, 8);
        v[q] = s;
      }
      if ((lane & 15) == 0) {
        const size_t bo = ((size_t)prow * 4 + (lane >> 4)) * PART + (size_t)(ch0 + cc) * 9;
        #pragma unroll
        for (int q = 0; q < 9; ++q) partials[bo + q] = v[q];
      }
    } else {
      #pragma unroll
      for (int q = 0; q < 9; ++q) {
        float s = v[q];
        #pragma unroll
        for (int m = 32; m >= 1; m >>= 1) s += __shfl_xor(s, m);
        v[q] = s;
      }
      if (lane == 0) {
        const size_t bo = (size_t)prow * PART + (size_t)(ch0 + cc) * 9;
        #pragma unroll
        for (int q = 0; q < 9; ++q) partials[bo + q] = v[q];
      }
    }
  }
}

// Per image: sum the 64*GROUPS partial rows (fixed order, deterministic),
// then contract with w2 via inclusion-exclusion border sums.
template<int GROUPS>
__global__ __launch_bounds__(192) void finish_kernel(
    const float* __restrict__ w2, const float* __restrict__ b2,
    const float* __restrict__ partials, float* __restrict__ out)
{
  const int img = blockIdx.x;
  const int tid = threadIdx.x;
  __shared__ float acc[C1N][9];
  if (tid < PART) {
    float s = 0.f;
    for (int k = 0; k < 64 * GROUPS; ++k)
      s += partials[((size_t)img * 64 * GROUPS + k) * PART + tid];
    acc[tid / 9][tid % 9] = s;
  }
  __syncthreads();
  if (tid < C2N) {
    float r = 0.f;
    for (int c1 = 0; c1 < C1N; ++c1) {
      const float T  = acc[c1][0], R0 = acc[c1][1], R7 = acc[c1][2];
      const float Q0 = acc[c1][3], Q7 = acc[c1][4];
      const float K00 = acc[c1][5], K07 = acc[c1][6], K70 = acc[c1][7], K77 = acc[c1][8];
      const float* wp = w2 + (size_t)(tid * C1N + c1) * 9;
      #pragma unroll
      for (int di = 0; di < 3; ++di) {
        #pragma unroll
        for (int dj = 0; dj < 3; ++dj) {
          float S = T;
          if (di == 0) S -= R7;
          if (di == 2) S -= R0;
          if (dj == 0) S -= Q7;
          if (dj == 2) S -= Q0;
          if (di == 0 && dj == 0) S += K77;
          if (di == 0 && dj == 2) S += K70;
          if (di == 2 && dj == 0) S += K07;
          if (di == 2 && dj == 2) S += K00;
          r = fmaf(wp[di * 3 + dj], S, r);
        }
      }
    }
    out[img * C2N + tid] = b2[tid] + r * (1.0f / 262144.0f);
  }
}

} // namespace

extern "C" void kernel_launch(void* const* d_in, const int* in_sizes, int n_in,
                              void* d_out, int out_size, void* d_ws, size_t ws_size,
                              hipStream_t stream) {
  const float* x  = (const float*)d_in[0];
  const float* w1 = (const float*)d_in[1];
  const float* b1 = (const float*)d_in[2];
  const float* w2 = (const float*)d_in[3];
  const float* b2 = (const float*)d_in[4];
  float* out      = (float*)d_out;
  float* partials = (float*)d_ws;

  const size_t need_g4 = (size_t)NROWS * 4 * PART * sizeof(float); // 2.36 MB
  if (ws_size >= need_g4) {
    dct_conv_kernel<4><<<NBLK, 64, 0, stream>>>(x, w1, b1, partials);
    finish_kernel<4><<<NIMG, 192, 0, stream>>>(w2, b2, partials, out);
  } else {
    dct_conv_kernel<1><<<NBLK, 64, 0, stream>>>(x, w1, b1, partials);
    finish_kernel<1><<<NIMG, 192, 0, stream>>>(w2, b2, partials, out);
  }
}

// Round 5
// 32.291 us; speedup vs baseline: 1.6207x; 1.6207x over previous
//
#include <hip/hip_runtime.h>

namespace {

constexpr int IMGW  = 512;
constexpr int NIMG  = 16;
constexpr int C1N   = 16;
constexpr int C2N   = 32;
constexpr int PART  = C1N * 9;   // 144 partial scalars per partial-row
constexpr int NROWS = 1024;      // total patch-rows (16 img x 64)

// Fast orthonormal 8-pt DCT-II (even/odd butterfly).
__device__ __forceinline__ void dct8(const float x[8], float o[8]) {
  const float c1 = 0.49039264020161522f;
  const float c2 = 0.46193976625564337f;
  const float c3 = 0.41573480615127262f;
  const float c4 = 0.35355339059327373f;
  const float c5 = 0.27778511650980111f;
  const float c6 = 0.19134171618254492f;
  const float c7 = 0.09754516100806413f;
  const float s0 = x[0] + x[7], s1 = x[1] + x[6], s2 = x[2] + x[5], s3 = x[3] + x[4];
  const float d0 = x[0] - x[7], d1 = x[1] - x[6], d2 = x[2] - x[5], d3 = x[3] - x[4];
  const float e0 = s0 + s3, e1 = s1 + s2, e2 = s0 - s3, e3 = s1 - s2;
  o[0] = c4 * (e0 + e1);
  o[4] = c4 * (e0 - e1);
  o[2] = fmaf(c2, e2,  c6 * e3);
  o[6] = fmaf(c6, e2, -(c2 * e3));
  o[1] = fmaf(c1, d0, fmaf( c3, d1, fmaf( c5, d2,  c7 * d3)));
  o[3] = fmaf(c3, d0, fmaf(-c7, d1, fmaf(-c1, d2, -(c5 * d3))));
  o[5] = fmaf(c5, d0, fmaf(-c1, d1, fmaf( c7, d2,  c3 * d3)));
  o[7] = fmaf(c7, d0, fmaf(-c5, d1, fmaf( c3, d2, -(c1 * d3))));
}

// One block = one patch-row (64 patches, lane = patch column); 4 waves,
// wave = channel quad. __launch_bounds__(256,2) -> 256-VGPR budget so
// p/t/cf all live in architectural VGPRs (no AGPR ping-pong; round-4's
// VGPR_Count=60 under a 128 cap with a >=192-float live set was the tell).
// GROUPS=4: DPP-only 4-level reduce, 4 partials/wave; GROUPS=1: full reduce.
template<int GROUPS>
__global__ __launch_bounds__(256, 2) void dct_conv_kernel(
    const float* __restrict__ x, const float* __restrict__ w1,
    const float* __restrict__ b1, float* __restrict__ partials)
{
  const int prow = blockIdx.x;         // img*64 + row
  const int img  = prow >> 6;
  const int row  = prow & 63;
  const int lane = threadIdx.x & 63;   // patch column
  const int wave = threadIdx.x >> 6;   // channel quad
  const int ch0  = wave * 4;

  // block-uniform weight loads -> SGPRs
  float w[4][9], bb[4];
  #pragma unroll
  for (int cc = 0; cc < 4; ++cc) {
    #pragma unroll
    for (int q = 0; q < 9; ++q) w[cc][q] = w1[(ch0 + cc) * 9 + q];
    bb[cc] = b1[ch0 + cc];
  }

  const float* base = x + ((size_t)img * IMGW + (size_t)row * 8) * IMGW + (size_t)lane * 8;

  float p[8][8];
  #pragma unroll
  for (int r = 0; r < 8; ++r) {
    const float4 a = *reinterpret_cast<const float4*>(base + (size_t)r * IMGW);
    const float4 b = *reinterpret_cast<const float4*>(base + (size_t)r * IMGW + 4);
    p[r][0] = a.x; p[r][1] = a.y; p[r][2] = a.z; p[r][3] = a.w;
    p[r][4] = b.x; p[r][5] = b.y; p[r][6] = b.z; p[r][7] = b.w;
  }

  // 2D DCT: t = D*p (column-wise), cf = t*D^T (row-wise)
  float t[8][8];
  #pragma unroll
  for (int j = 0; j < 8; ++j) {
    float xin[8], xo[8];
    #pragma unroll
    for (int k = 0; k < 8; ++k) xin[k] = p[k][j];
    dct8(xin, xo);
    #pragma unroll
    for (int k = 0; k < 8; ++k) t[k][j] = xo[k];
  }
  float cf[8][8];
  #pragma unroll
  for (int i = 0; i < 8; ++i) {
    float xo[8];
    dct8(t[i], xo);
    #pragma unroll
    for (int k = 0; k < 8; ++k) cf[i][k] = xo[k];
  }

  // conv1 3x3 SAME + ReLU, row-structured; immediate per-channel reduce.
  #pragma unroll
  for (int cc = 0; cc < 4; ++cc) {
    const float bbc = bb[cc];
    float T = 0.f, C0 = 0.f, C7 = 0.f;
    float R0 = 0.f, R7 = 0.f, K00 = 0.f, K07 = 0.f, K70 = 0.f, K77 = 0.f;
    #pragma unroll
    for (int i = 0; i < 8; ++i) {
      float a[8];
      #pragma unroll
      for (int j = 0; j < 8; ++j) a[j] = bbc;
      #pragma unroll
      for (int di = 0; di < 3; ++di) {
        const int ii = i + di - 1;
        if (ii >= 0 && ii < 8) {
          const float w0 = w[cc][di * 3 + 0];
          const float w1_ = w[cc][di * 3 + 1];
          const float w2_ = w[cc][di * 3 + 2];
          a[0] = fmaf(w1_, cf[ii][0], fmaf(w2_, cf[ii][1], a[0]));
          #pragma unroll
          for (int j = 1; j < 7; ++j)
            a[j] = fmaf(w0, cf[ii][j - 1], fmaf(w1_, cf[ii][j], fmaf(w2_, cf[ii][j + 1], a[j])));
          a[7] = fmaf(w0, cf[ii][6], fmaf(w1_, cf[ii][7], a[7]));
        }
      }
      #pragma unroll
      for (int j = 0; j < 8; ++j) a[j] = fmaxf(a[j], 0.f);
      const float rs = ((a[0] + a[1]) + (a[2] + a[3])) + ((a[4] + a[5]) + (a[6] + a[7]));
      T += rs;
      C0 += a[0]; C7 += a[7];
      if (i == 0) { R0 = rs; K00 = a[0]; K07 = a[7]; }
      if (i == 7) { R7 = rs; K70 = a[0]; K77 = a[7]; }
    }

    float v[9] = {T, R0, R7, C0, C7, K00, K07, K70, K77};
    if (GROUPS == 4) {
      #pragma unroll
      for (int q = 0; q < 9; ++q) {
        float s = v[q];
        s += __shfl_xor(s, 1); s += __shfl_xor(s, 2);
        s += __shfl_xor(s, 4); s += __shfl_xor(s, 8);
        v[q] = s;
      }
      if ((lane & 15) == 0) {
        const size_t bo = ((size_t)prow * 4 + (lane >> 4)) * PART + (size_t)(ch0 + cc) * 9;
        #pragma unroll
        for (int q = 0; q < 9; ++q) partials[bo + q] = v[q];
      }
    } else {
      #pragma unroll
      for (int q = 0; q < 9; ++q) {
        float s = v[q];
        #pragma unroll
        for (int m = 32; m >= 1; m >>= 1) s += __shfl_xor(s, m);
        v[q] = s;
      }
      if (lane == 0) {
        const size_t bo = (size_t)prow * PART + (size_t)(ch0 + cc) * 9;
        #pragma unroll
        for (int q = 0; q < 9; ++q) partials[bo + q] = v[q];
      }
    }
  }
}

// Per image: 576 threads = 4 chunks x 144 components; chunked strided sums
// (parallel, latency-friendly) -> LDS -> fixed-order combine -> w2
// contraction via inclusion-exclusion border sums. Fully deterministic.
template<int GROUPS>
__global__ __launch_bounds__(576) void finish_kernel(
    const float* __restrict__ w2, const float* __restrict__ b2,
    const float* __restrict__ partials, float* __restrict__ out)
{
  const int img  = blockIdx.x;
  const int tid  = threadIdx.x;
  const int comp = tid % PART;
  const int chnk = tid / PART;         // 0..3
  constexpr int ROWS = 64 * GROUPS;    // partial-rows per image
  constexpr int RPC  = ROWS / 4;       // rows per chunk

  __shared__ float part[4][PART];
  __shared__ float acc[C1N][9];

  {
    float s = 0.f;
    const float* pb = partials + ((size_t)img * ROWS + (size_t)chnk * RPC) * PART + comp;
    for (int k = 0; k < RPC; ++k) s += pb[(size_t)k * PART];
    part[chnk][comp] = s;
  }
  __syncthreads();
  if (tid < PART) {
    const float s = ((part[0][tid] + part[1][tid]) + (part[2][tid] + part[3][tid]));
    acc[tid / 9][tid % 9] = s;
  }
  __syncthreads();
  if (tid < C2N) {
    float r = 0.f;
    for (int c1 = 0; c1 < C1N; ++c1) {
      const float T  = acc[c1][0], R0 = acc[c1][1], R7 = acc[c1][2];
      const float Q0 = acc[c1][3], Q7 = acc[c1][4];
      const float K00 = acc[c1][5], K07 = acc[c1][6], K70 = acc[c1][7], K77 = acc[c1][8];
      const float* wp = w2 + (size_t)(tid * C1N + c1) * 9;
      #pragma unroll
      for (int di = 0; di < 3; ++di) {
        #pragma unroll
        for (int dj = 0; dj < 3; ++dj) {
          float S = T;
          if (di == 0) S -= R7;
          if (di == 2) S -= R0;
          if (dj == 0) S -= Q7;
          if (dj == 2) S -= Q0;
          if (di == 0 && dj == 0) S += K77;
          if (di == 0 && dj == 2) S += K70;
          if (di == 2 && dj == 0) S += K07;
          if (di == 2 && dj == 2) S += K00;
          r = fmaf(wp[di * 3 + dj], S, r);
        }
      }
    }
    out[img * C2N + tid] = b2[tid] + r * (1.0f / 262144.0f);
  }
}

} // namespace

extern "C" void kernel_launch(void* const* d_in, const int* in_sizes, int n_in,
                              void* d_out, int out_size, void* d_ws, size_t ws_size,
                              hipStream_t stream) {
  const float* x  = (const float*)d_in[0];
  const float* w1 = (const float*)d_in[1];
  const float* b1 = (const float*)d_in[2];
  const float* w2 = (const float*)d_in[3];
  const float* b2 = (const float*)d_in[4];
  float* out      = (float*)d_out;
  float* partials = (float*)d_ws;

  const size_t need_g4 = (size_t)NROWS * 4 * PART * sizeof(float); // 2.36 MB
  if (ws_size >= need_g4) {
    dct_conv_kernel<4><<<NROWS, 256, 0, stream>>>(x, w1, b1, partials);
    finish_kernel<4><<<NIMG, 576, 0, stream>>>(w2, b2, partials, out);
  } else {
    dct_conv_kernel<1><<<NROWS, 256, 0, stream>>>(x, w1, b1, partials);
    finish_kernel<1><<<NIMG, 576, 0, stream>>>(w2, b2, partials, out);
  }
}

// Round 6
// 31.690 us; speedup vs baseline: 1.6514x; 1.0190x over previous
//
#include <hip/hip_runtime.h>

namespace {

constexpr int IMGW  = 512;
constexpr int NIMG  = 16;
constexpr int C1N   = 16;
constexpr int C2N   = 32;
constexpr int PART  = C1N * 9;   // 144 partial scalars per partial-row
constexpr int NROWS = 1024;      // total patch-rows (16 img x 64)

// Fast orthonormal 8-pt DCT-II (even/odd butterfly).
__device__ __forceinline__ void dct8(const float x[8], float o[8]) {
  const float c1 = 0.49039264020161522f;
  const float c2 = 0.46193976625564337f;
  const float c3 = 0.41573480615127262f;
  const float c4 = 0.35355339059327373f;
  const float c5 = 0.27778511650980111f;
  const float c6 = 0.19134171618254492f;
  const float c7 = 0.09754516100806413f;
  const float s0 = x[0] + x[7], s1 = x[1] + x[6], s2 = x[2] + x[5], s3 = x[3] + x[4];
  const float d0 = x[0] - x[7], d1 = x[1] - x[6], d2 = x[2] - x[5], d3 = x[3] - x[4];
  const float e0 = s0 + s3, e1 = s1 + s2, e2 = s0 - s3, e3 = s1 - s2;
  o[0] = c4 * (e0 + e1);
  o[4] = c4 * (e0 - e1);
  o[2] = fmaf(c2, e2,  c6 * e3);
  o[6] = fmaf(c6, e2, -(c2 * e3));
  o[1] = fmaf(c1, d0, fmaf( c3, d1, fmaf( c5, d2,  c7 * d3)));
  o[3] = fmaf(c3, d0, fmaf(-c7, d1, fmaf(-c1, d2, -(c5 * d3))));
  o[5] = fmaf(c5, d0, fmaf(-c1, d1, fmaf( c7, d2,  c3 * d3)));
  o[7] = fmaf(c7, d0, fmaf(-c5, d1, fmaf( c3, d2, -(c1 * d3))));
}

// One block = one patch-row (64 patches, lane = patch column); 4 waves,
// wave = channel quad. Channel loop is ROLLED (#pragma unroll 1): the
// conv+reduce body is emitted ONCE (~11 KB total vs ~30 KB unrolled) to
// stay well inside the 32 KB I$ — theory: rounds 1-5 were I-fetch bound
// (VALUBusy pinned ~40% regardless of occupancy/work/config).
// Weights are wave-uniform scalar loads per iteration (named scalars ->
// static register indexing, no scratch).
// GROUPS=4: DPP-only 4-level reduce, 4 partials/wave; GROUPS=1: full reduce.
template<int GROUPS>
__global__ __launch_bounds__(256, 2) void dct_conv_kernel(
    const float* __restrict__ x, const float* __restrict__ w1,
    const float* __restrict__ b1, float* __restrict__ partials)
{
  const int prow = blockIdx.x;         // img*64 + row
  const int img  = prow >> 6;
  const int row  = prow & 63;
  const int lane = threadIdx.x & 63;   // patch column
  const int wave = threadIdx.x >> 6;   // channel quad
  const int ch0  = wave * 4;

  const float* base = x + ((size_t)img * IMGW + (size_t)row * 8) * IMGW + (size_t)lane * 8;

  float p[8][8];
  #pragma unroll
  for (int r = 0; r < 8; ++r) {
    const float4 a = *reinterpret_cast<const float4*>(base + (size_t)r * IMGW);
    const float4 b = *reinterpret_cast<const float4*>(base + (size_t)r * IMGW + 4);
    p[r][0] = a.x; p[r][1] = a.y; p[r][2] = a.z; p[r][3] = a.w;
    p[r][4] = b.x; p[r][5] = b.y; p[r][6] = b.z; p[r][7] = b.w;
  }

  // 2D DCT: t = D*p (column-wise), cf = t*D^T (row-wise)
  float t[8][8];
  #pragma unroll
  for (int j = 0; j < 8; ++j) {
    float xin[8], xo[8];
    #pragma unroll
    for (int k = 0; k < 8; ++k) xin[k] = p[k][j];
    dct8(xin, xo);
    #pragma unroll
    for (int k = 0; k < 8; ++k) t[k][j] = xo[k];
  }
  float cf[8][8];
  #pragma unroll
  for (int i = 0; i < 8; ++i) {
    float xo[8];
    dct8(t[i], xo);
    #pragma unroll
    for (int k = 0; k < 8; ++k) cf[i][k] = xo[k];
  }

  // conv1 3x3 SAME + ReLU, one channel at a time (rolled loop).
  #pragma unroll 1
  for (int cc = 0; cc < 4; ++cc) {
    const float* wp = w1 + (size_t)(ch0 + cc) * 9;   // wave-uniform -> s_load
    const float w0 = wp[0], w1_ = wp[1], w2_ = wp[2];
    const float w3 = wp[3], w4_ = wp[4], w5_ = wp[5];
    const float w6 = wp[6], w7_ = wp[7], w8_ = wp[8];
    const float bbc = b1[ch0 + cc];

    float T = 0.f, C0 = 0.f, C7 = 0.f;
    float R0 = 0.f, R7 = 0.f, K00 = 0.f, K07 = 0.f, K70 = 0.f, K77 = 0.f;
    #pragma unroll
    for (int i = 0; i < 8; ++i) {
      float a[8];
      #pragma unroll
      for (int j = 0; j < 8; ++j) a[j] = bbc;
      // di = 0 (row i-1)
      if (i > 0) {
        a[0] = fmaf(w1_, cf[i-1][0], fmaf(w2_, cf[i-1][1], a[0]));
        #pragma unroll
        for (int j = 1; j < 7; ++j)
          a[j] = fmaf(w0, cf[i-1][j-1], fmaf(w1_, cf[i-1][j], fmaf(w2_, cf[i-1][j+1], a[j])));
        a[7] = fmaf(w0, cf[i-1][6], fmaf(w1_, cf[i-1][7], a[7]));
      }
      // di = 1 (row i)
      {
        a[0] = fmaf(w4_, cf[i][0], fmaf(w5_, cf[i][1], a[0]));
        #pragma unroll
        for (int j = 1; j < 7; ++j)
          a[j] = fmaf(w3, cf[i][j-1], fmaf(w4_, cf[i][j], fmaf(w5_, cf[i][j+1], a[j])));
        a[7] = fmaf(w3, cf[i][6], fmaf(w4_, cf[i][7], a[7]));
      }
      // di = 2 (row i+1)
      if (i < 7) {
        a[0] = fmaf(w7_, cf[i+1][0], fmaf(w8_, cf[i+1][1], a[0]));
        #pragma unroll
        for (int j = 1; j < 7; ++j)
          a[j] = fmaf(w6, cf[i+1][j-1], fmaf(w7_, cf[i+1][j], fmaf(w8_, cf[i+1][j+1], a[j])));
        a[7] = fmaf(w6, cf[i+1][6], fmaf(w7_, cf[i+1][7], a[7]));
      }
      #pragma unroll
      for (int j = 0; j < 8; ++j) a[j] = fmaxf(a[j], 0.f);
      const float rs = ((a[0] + a[1]) + (a[2] + a[3])) + ((a[4] + a[5]) + (a[6] + a[7]));
      T += rs;
      C0 += a[0]; C7 += a[7];
      if (i == 0) { R0 = rs; K00 = a[0]; K07 = a[7]; }
      if (i == 7) { R7 = rs; K70 = a[0]; K77 = a[7]; }
    }

    float v[9] = {T, R0, R7, C0, C7, K00, K07, K70, K77};
    if (GROUPS == 4) {
      #pragma unroll
      for (int q = 0; q < 9; ++q) {
        float s = v[q];
        s += __shfl_xor(s, 1); s += __shfl_xor(s, 2);
        s += __shfl_xor(s, 4); s += __shfl_xor(s, 8);
        v[q] = s;
      }
      if ((lane & 15) == 0) {
        const size_t bo = ((size_t)prow * 4 + (lane >> 4)) * PART + (size_t)(ch0 + cc) * 9;
        #pragma unroll
        for (int q = 0; q < 9; ++q) partials[bo + q] = v[q];
      }
    } else {
      #pragma unroll
      for (int q = 0; q < 9; ++q) {
        float s = v[q];
        #pragma unroll
        for (int m = 32; m >= 1; m >>= 1) s += __shfl_xor(s, m);
        v[q] = s;
      }
      if (lane == 0) {
        const size_t bo = (size_t)prow * PART + (size_t)(ch0 + cc) * 9;
        #pragma unroll
        for (int q = 0; q < 9; ++q) partials[bo + q] = v[q];
      }
    }
  }
}

// Per image: 576 threads = 4 chunks x 144 components; chunked strided sums
// -> LDS -> fixed-order combine -> w2 contraction via inclusion-exclusion
// border sums. Fully deterministic.
template<int GROUPS>
__global__ __launch_bounds__(576) void finish_kernel(
    const float* __restrict__ w2, const float* __restrict__ b2,
    const float* __restrict__ partials, float* __restrict__ out)
{
  const int img  = blockIdx.x;
  const int tid  = threadIdx.x;
  const int comp = tid % PART;
  const int chnk = tid / PART;         // 0..3
  constexpr int ROWS = 64 * GROUPS;    // partial-rows per image
  constexpr int RPC  = ROWS / 4;       // rows per chunk

  __shared__ float part[4][PART];
  __shared__ float acc[C1N][9];

  {
    float s = 0.f;
    const float* pb = partials + ((size_t)img * ROWS + (size_t)chnk * RPC) * PART + comp;
    for (int k = 0; k < RPC; ++k) s += pb[(size_t)k * PART];
    part[chnk][comp] = s;
  }
  __syncthreads();
  if (tid < PART) {
    const float s = ((part[0][tid] + part[1][tid]) + (part[2][tid] + part[3][tid]));
    acc[tid / 9][tid % 9] = s;
  }
  __syncthreads();
  if (tid < C2N) {
    float r = 0.f;
    for (int c1 = 0; c1 < C1N; ++c1) {
      const float T  = acc[c1][0], R0 = acc[c1][1], R7 = acc[c1][2];
      const float Q0 = acc[c1][3], Q7 = acc[c1][4];
      const float K00 = acc[c1][5], K07 = acc[c1][6], K70 = acc[c1][7], K77 = acc[c1][8];
      const float* wp = w2 + (size_t)(tid * C1N + c1) * 9;
      #pragma unroll
      for (int di = 0; di < 3; ++di) {
        #pragma unroll
        for (int dj = 0; dj < 3; ++dj) {
          float S = T;
          if (di == 0) S -= R7;
          if (di == 2) S -= R0;
          if (dj == 0) S -= Q7;
          if (dj == 2) S -= Q0;
          if (di == 0 && dj == 0) S += K77;
          if (di == 0 && dj == 2) S += K70;
          if (di == 2 && dj == 0) S += K07;
          if (di == 2 && dj == 2) S += K00;
          r = fmaf(wp[di * 3 + dj], S, r);
        }
      }
    }
    out[img * C2N + tid] = b2[tid] + r * (1.0f / 262144.0f);
  }
}

} // namespace

extern "C" void kernel_launch(void* const* d_in, const int* in_sizes, int n_in,
                              void* d_out, int out_size, void* d_ws, size_t ws_size,
                              hipStream_t stream) {
  const float* x  = (const float*)d_in[0];
  const float* w1 = (const float*)d_in[1];
  const float* b1 = (const float*)d_in[2];
  const float* w2 = (const float*)d_in[3];
  const float* b2 = (const float*)d_in[4];
  float* out      = (float*)d_out;
  float* partials = (float*)d_ws;

  const size_t need_g4 = (size_t)NROWS * 4 * PART * sizeof(float); // 2.36 MB
  if (ws_size >= need_g4) {
    dct_conv_kernel<4><<<NROWS, 256, 0, stream>>>(x, w1, b1, partials);
    finish_kernel<4><<<NIMG, 576, 0, stream>>>(w2, b2, partials, out);
  } else {
    dct_conv_kernel<1><<<NROWS, 256, 0, stream>>>(x, w1, b1, partials);
    finish_kernel<1><<<NIMG, 576, 0, stream>>>(w2, b2, partials, out);
  }
}

// Round 7
// 31.546 us; speedup vs baseline: 1.6590x; 1.0046x over previous
//
#include <hip/hip_runtime.h>

namespace {

constexpr int NIMG = 16;
constexpr int C1N  = 16;
constexpr int C2N  = 32;
constexpr int PART = C1N * 9;     // 144 partial scalars per partial-row

typedef __attribute__((ext_vector_type(8)))  _Float16 half8;
typedef __attribute__((ext_vector_type(16))) float    f32x16;

// Orthonormal 8-pt DCT-II matrix (f32-exact literals).
__device__ const float DCTM[8][8] = {
  {0.35355339059327373f, 0.35355339059327373f, 0.35355339059327373f, 0.35355339059327373f,
   0.35355339059327373f, 0.35355339059327373f, 0.35355339059327373f, 0.35355339059327373f},
  {0.49039264020161522f, 0.41573480615127262f, 0.27778511650980111f, 0.09754516100806413f,
  -0.09754516100806413f,-0.27778511650980111f,-0.41573480615127262f,-0.49039264020161522f},
  {0.46193976625564337f, 0.19134171618254492f,-0.19134171618254492f,-0.46193976625564337f,
  -0.46193976625564337f,-0.19134171618254492f, 0.19134171618254492f, 0.46193976625564337f},
  {0.41573480615127262f,-0.09754516100806413f,-0.49039264020161522f,-0.27778511650980111f,
   0.27778511650980111f, 0.49039264020161522f, 0.09754516100806413f,-0.41573480615127262f},
  {0.35355339059327373f,-0.35355339059327373f,-0.35355339059327373f, 0.35355339059327373f,
   0.35355339059327373f,-0.35355339059327373f,-0.35355339059327373f, 0.35355339059327373f},
  {0.27778511650980111f,-0.49039264020161522f, 0.09754516100806413f, 0.41573480615127262f,
  -0.41573480615127262f,-0.09754516100806413f, 0.49039264020161522f,-0.27778511650980111f},
  {0.19134171618254492f,-0.46193976625564337f, 0.46193976625564337f,-0.19134171618254492f,
  -0.19134171618254492f, 0.46193976625564337f,-0.46193976625564337f, 0.19134171618254492f},
  {0.09754516100806413f,-0.27778511650980111f, 0.41573480615127262f,-0.49039264020161522f,
   0.49039264020161522f,-0.41573480615127262f, 0.27778511650980111f,-0.09754516100806413f},
};

// Build M (1024 x 80, fp16) directly in A-fragment order for
// v_mfma_f32_32x32x16_f16: frag f = (rt*5 + c)*64 + lane holds
// A[row = rt*32 + (lane&31), k = c*16 + (lane>>5)*8 + b], b = 0..7.
// M[(ch,i,j),(u,v)] = sum_{di,dj} w1[ch,di,dj] * D[i+di-1,u] * D[j+dj-1,v]
// (zero outside bounds). k-chunk 4 is the bias column: M[r,64] = b1[ch],
// with a ones-B fragment supplying p[64] = 1 -> bias folded into the MFMA.
__global__ __launch_bounds__(256) void setup_M(
    const float* __restrict__ w1, const float* __restrict__ b1,
    _Float16* __restrict__ Mf)
{
  const int f = blockIdx.x * 256 + threadIdx.x;
  if (f >= 32 * 5 * 64) return;
  const int l  = f & 63;
  const int rc = f >> 6;
  const int c  = rc % 5;
  const int rt = rc / 5;
  const int ch = rt >> 1;
  const int hi = l >> 5;
  const int s  = (rt & 1) * 32 + (l & 31);
  const int i = s >> 3, j = s & 7;

  half8 e;
  if (c == 4) {
    #pragma unroll
    for (int b = 0; b < 8; ++b) e[b] = (_Float16)0.f;
    if (hi == 0) e[0] = (_Float16)b1[ch];
  } else {
    #pragma unroll
    for (int b = 0; b < 8; ++b) {
      const int k = c * 16 + hi * 8 + b;
      const int u = k >> 3, v = k & 7;
      float acc = 0.f;
      for (int di = 0; di < 3; ++di) {
        const int ii = i + di - 1;
        if (ii < 0 || ii > 7) continue;
        for (int dj = 0; dj < 3; ++dj) {
          const int jj = j + dj - 1;
          if (jj < 0 || jj > 7) continue;
          acc = fmaf(w1[ch * 9 + di * 3 + dj], DCTM[ii][u] * DCTM[jj][v], acc);
        }
      }
      e[b] = (_Float16)acc;
    }
  }
  *reinterpret_cast<half8*>(Mf + (size_t)f * 8) = e;
}

// One block = one wave. bid = slice*512 + g; slice -> 4 conv1 channels
// (8 row-tiles of M), g -> 128 patches (4 col-tiles of 32) of image g>>5.
// B-fragments: lane holds pixels k=(lane>>5)*8+b of patch (lane&31), i.e.
// patch row u = 2m + (lane>>5) for K-chunk m — loaded as 2 float4 and cast
// to fp16. D tile (verified m74/m101): col = lane&31 = patch,
// row = (reg&3) + 8*(reg>>2) + 4*(lane>>5); with s = (rt&1)*32 + row:
// i = 4*(rt&1) + (reg>>2) (compile-time), j = (reg&3) + 4*hi (hi-pred).
// Epilogue: ReLU + compress to 9 border-class sums per channel (conv2 and
// both means are linear -> fold into finish via inclusion-exclusion).
__global__ __launch_bounds__(64, 2) void gemm_kernel(
    const float* __restrict__ x, const _Float16* __restrict__ Mf,
    float* __restrict__ partials)
{
  const int bid   = blockIdx.x;
  const int slice = bid >> 9;          // 0..3 -> channels 4*slice..+3
  const int g     = bid & 511;         // global col-group
  const int img   = g >> 5, gi = g & 31;
  const int lane  = threadIdx.x;
  const int col   = lane & 31, hi = lane >> 5;

  // Stage B: 4 col-tiles x 4 K-chunks of fp16 patch data.
  half8 bfrag[4][4];
  #pragma unroll
  for (int ct = 0; ct < 4; ++ct) {
    const int prow = 2 * gi + (ct >> 1);
    const int pcol = (ct & 1) * 32 + col;
    const float* pb = x + (((size_t)img * 512 + (size_t)prow * 8) * 512 + (size_t)pcol * 8);
    #pragma unroll
    for (int m = 0; m < 4; ++m) {
      const int u = 2 * m + hi;
      const float4 lo = *reinterpret_cast<const float4*>(pb + (size_t)u * 512);
      const float4 h4 = *reinterpret_cast<const float4*>(pb + (size_t)u * 512 + 4);
      half8 h;
      h[0] = (_Float16)lo.x; h[1] = (_Float16)lo.y; h[2] = (_Float16)lo.z; h[3] = (_Float16)lo.w;
      h[4] = (_Float16)h4.x; h[5] = (_Float16)h4.y; h[6] = (_Float16)h4.z; h[7] = (_Float16)h4.w;
      bfrag[ct][m] = h;
    }
  }
  const float hm0 = (hi == 0) ? 1.f : 0.f;
  const float hm1 = 1.f - hm0;
  half8 bones;                          // B for the bias K-chunk: p[k=64] = 1
  #pragma unroll
  for (int b = 0; b < 8; ++b) bones[b] = (_Float16)0.f;
  bones[0] = (_Float16)hm0;

  #pragma unroll 1
  for (int cc = 0; cc < 4; ++cc) {      // channel within slice
    float t_ = 0.f, r0 = 0.f, r7 = 0.f, c0 = 0.f, c7 = 0.f;
    float k00 = 0.f, k07 = 0.f, k70 = 0.f, k77 = 0.f;
    #pragma unroll
    for (int rp = 0; rp < 2; ++rp) {    // row-tile pair of this channel
      const int rtg = slice * 8 + cc * 2 + rp;
      const _Float16* ap = Mf + ((size_t)(rtg * 5) * 64 + (size_t)lane) * 8;
      const half8 a0 = *reinterpret_cast<const half8*>(ap);
      const half8 a1 = *reinterpret_cast<const half8*>(ap + 512);
      const half8 a2 = *reinterpret_cast<const half8*>(ap + 1024);
      const half8 a3 = *reinterpret_cast<const half8*>(ap + 1536);
      const half8 a4 = *reinterpret_cast<const half8*>(ap + 2048);
      #pragma unroll
      for (int ct = 0; ct < 4; ++ct) {
        f32x16 d;
        #pragma unroll
        for (int r = 0; r < 16; ++r) d[r] = 0.f;
        d = __builtin_amdgcn_mfma_f32_32x32x16_f16(a0, bfrag[ct][0], d, 0, 0, 0);
        d = __builtin_amdgcn_mfma_f32_32x32x16_f16(a1, bfrag[ct][1], d, 0, 0, 0);
        d = __builtin_amdgcn_mfma_f32_32x32x16_f16(a2, bfrag[ct][2], d, 0, 0, 0);
        d = __builtin_amdgcn_mfma_f32_32x32x16_f16(a3, bfrag[ct][3], d, 0, 0, 0);
        d = __builtin_amdgcn_mfma_f32_32x32x16_f16(a4, bones,        d, 0, 0, 0);

        float v[16];
        #pragma unroll
        for (int r = 0; r < 16; ++r) v[r] = fmaxf(d[r], 0.f);
        const float q0 = (v[0]  + v[1])  + (v[2]  + v[3]);
        const float q1 = (v[4]  + v[5])  + (v[6]  + v[7]);
        const float q2 = (v[8]  + v[9])  + (v[10] + v[11]);
        const float q3 = (v[12] + v[13]) + (v[14] + v[15]);
        t_ += (q0 + q1) + (q2 + q3);
        if (rp == 0) {                   // rows i = 0..3 -> contains i==0
          r0 += q0;                      // regs 0..3 are i==0
          k00 = fmaf(hm0, v[0],  k00);   // (0,0)
          k07 = fmaf(hm1, v[3],  k07);   // (0,7)
        } else {                         // rows i = 4..7 -> contains i==7
          r7 += q3;                      // regs 12..15 are i==7
          k70 = fmaf(hm0, v[12], k70);   // (7,0)
          k77 = fmaf(hm1, v[15], k77);   // (7,7)
        }
        c0 = fmaf(hm0, (v[0] + v[4]) + (v[8]  + v[12]), c0);  // j==0
        c7 = fmaf(hm1, (v[3] + v[7]) + (v[11] + v[15]), c7);  // j==7
      }
    }
    // 4-level reduce (lanes bits 0..3); lanes 0/16/32/48 write partials.
    float vv[9] = {t_, r0, r7, c0, c7, k00, k07, k70, k77};
    #pragma unroll
    for (int q = 0; q < 9; ++q) {
      float s = vv[q];
      s += __shfl_xor(s, 1); s += __shfl_xor(s, 2);
      s += __shfl_xor(s, 4); s += __shfl_xor(s, 8);
      vv[q] = s;
    }
    if ((lane & 15) == 0) {
      const size_t prw = (size_t)g * 4 + (lane >> 4);
      float* dst = partials + prw * PART + (size_t)(slice * 4 + cc) * 9;
      #pragma unroll
      for (int q = 0; q < 9; ++q) dst[q] = vv[q];
    }
  }
}

// Per image: sum its 128 partial-rows (fixed order, deterministic) ->
// acc[16][9] -> contract with w2 via inclusion-exclusion border sums.
__global__ __launch_bounds__(576) void finish_kernel(
    const float* __restrict__ w2, const float* __restrict__ b2,
    const float* __restrict__ partials, float* __restrict__ out)
{
  const int img  = blockIdx.x;
  const int tid  = threadIdx.x;
  const int comp = tid % PART;
  const int chnk = tid / PART;         // 0..3

  __shared__ float part[4][PART];
  __shared__ float acc[C1N][9];

  {
    float s = 0.f;
    const float* pb = partials + ((size_t)img * 128 + (size_t)chnk * 32) * PART + comp;
    for (int k = 0; k < 32; ++k) s += pb[(size_t)k * PART];
    part[chnk][comp] = s;
  }
  __syncthreads();
  if (tid < PART) {
    acc[tid / 9][tid % 9] = (part[0][tid] + part[1][tid]) + (part[2][tid] + part[3][tid]);
  }
  __syncthreads();
  if (tid < C2N) {
    float r = 0.f;
    for (int c1 = 0; c1 < C1N; ++c1) {
      const float T  = acc[c1][0], R0 = acc[c1][1], R7 = acc[c1][2];
      const float Q0 = acc[c1][3], Q7 = acc[c1][4];
      const float K00 = acc[c1][5], K07 = acc[c1][6], K70 = acc[c1][7], K77 = acc[c1][8];
      const float* wp = w2 + (size_t)(tid * C1N + c1) * 9;
      #pragma unroll
      for (int di = 0; di < 3; ++di) {
        #pragma unroll
        for (int dj = 0; dj < 3; ++dj) {
          float S = T;
          if (di == 0) S -= R7;
          if (di == 2) S -= R0;
          if (dj == 0) S -= Q7;
          if (dj == 2) S -= Q0;
          if (di == 0 && dj == 0) S += K77;
          if (di == 0 && dj == 2) S += K70;
          if (di == 2 && dj == 0) S += K07;
          if (di == 2 && dj == 2) S += K00;
          r = fmaf(wp[di * 3 + dj], S, r);
        }
      }
    }
    out[img * C2N + tid] = b2[tid] + r * (1.0f / 262144.0f);
  }
}

} // namespace

extern "C" void kernel_launch(void* const* d_in, const int* in_sizes, int n_in,
                              void* d_out, int out_size, void* d_ws, size_t ws_size,
                              hipStream_t stream) {
  const float* x  = (const float*)d_in[0];
  const float* w1 = (const float*)d_in[1];
  const float* b1 = (const float*)d_in[2];
  const float* w2 = (const float*)d_in[3];
  const float* b2 = (const float*)d_in[4];
  float* out      = (float*)d_out;

  // d_ws layout: [0, 160KB) = M fragments (fp16); [256KB, ~1.4MB) = partials.
  _Float16* Mf    = (_Float16*)d_ws;
  float* partials = (float*)((char*)d_ws + 262144);

  setup_M<<<40, 256, 0, stream>>>(w1, b1, Mf);
  gemm_kernel<<<2048, 64, 0, stream>>>(x, Mf, partials);
  finish_kernel<<<NIMG, 576, 0, stream>>>(w2, b2, partials, out);
}